// Round 1
// baseline (363.191 us; speedup 1.0000x reference)
//
#include <hip/hip_runtime.h>
#include <math.h>

#define DIM 64
#define KC 32
#define NPTS 32768
#define LOG_2PI 1.8378770664093453f

// ============================================================================
// Prep: per-k (32 blocks, 64 threads = 1 wave):
//   Sigma = tril(L) tril(L)^T + I  -> Cholesky C -> M = C^{-1} (lower),
//   q = M mu, const_k = -0.5*(D*log2pi + logdet) + log_softmax(w)_k
// ============================================================================
__global__ __launch_bounds__(64) void prep_kernel(
    const float* __restrict__ L, const float* __restrict__ mu,
    const float* __restrict__ w, float* __restrict__ Mout,
    float* __restrict__ qout, float* __restrict__ cout)
{
    const int k = blockIdx.x;
    const int t = threadIdx.x;  // 0..63
    __shared__ float Ls[DIM][DIM + 1];   // tril(L), later reused as M
    __shared__ float sig[DIM][DIM + 1];  // Sigma, then C (lower)
    __shared__ float diaglog[DIM];

    // load tril(L) (zeros above diag -> enables uniform-bound loops below)
    for (int idx = t; idx < DIM * DIM; idx += 64) {
        int r = idx >> 6, c = idx & 63;
        float v = L[k * DIM * DIM + idx];
        Ls[r][c] = (c <= r) ? v : 0.f;
    }
    __syncthreads();

    // Sigma row i (uniform i-loop; lane = column j). Upper-tril zeros in Ls
    // make sum_{l<=i} Ls[i][l]*Ls[j][l] == sum_{l<=min(i,j)} automatically.
    for (int i = 0; i < DIM; ++i) {
        float s = 0.f;
        for (int l = 0; l <= i; ++l) s = fmaf(Ls[i][l], Ls[t][l], s);
        if (i == t) s += 1.f;
        sig[i][t] = s;
    }
    __syncthreads();

    // Cholesky, right-looking, lower in place (single wave; barriers cheap)
    for (int c = 0; c < DIM; ++c) {
        float d = sqrtf(sig[c][c]);
        float val = (t == c) ? d : ((t > c) ? sig[t][c] / d : 0.f);
        __syncthreads();
        if (t >= c) sig[t][c] = val;
        __syncthreads();
        if (t > c) {
            float lic = val;
            for (int j = c + 1; j <= t; ++j) sig[t][j] -= lic * sig[j][c];
        }
        __syncthreads();
    }
    diaglog[t] = logf(sig[t][t]);
    __syncthreads();

    // M = C^{-1}: row recurrence, lane = column j. Each lane touches only its
    // own column of Ls (no cross-lane hazards -> no barriers needed).
    {
        const int j = t;
        for (int i = 0; i < DIM; ++i) {
            float s = (i == j) ? 1.f : 0.f;
            for (int l = 0; l < i; ++l) s = fmaf(-sig[i][l], Ls[l][j], s);
            Ls[i][j] = (j <= i) ? s / sig[i][i] : 0.f;
        }
    }
    __syncthreads();

    // write M dense (coalesced)
    for (int idx = t; idx < DIM * DIM; idx += 64)
        Mout[k * DIM * DIM + idx] = Ls[idx >> 6][idx & 63];

    // q = M * mu_k (thread i computes q_i)
    {
        float s = 0.f;
        for (int j = 0; j <= t; ++j) s = fmaf(Ls[t][j], mu[k * DIM + j], s);
        qout[k * DIM + t] = s;
    }

    if (t == 0) {
        float ld = 0.f;
        for (int i = 0; i < DIM; ++i) ld += diaglog[i];
        ld *= 2.f;
        float wm = -3.0e38f;
        for (int i = 0; i < KC; ++i) wm = fmaxf(wm, w[i]);
        float se = 0.f;
        for (int i = 0; i < KC; ++i) se += __expf(w[i] - wm);
        float logw = w[k] - (wm + logf(se));
        cout[k] = -0.5f * (DIM * LOG_2PI + ld) + logw;
    }
}

// ============================================================================
// Main: 512 blocks x 512 threads. lane = row n (64 rows/block), each of the
// 8 waves handles 4 of the 32 components; logsumexp merged across waves via
// LDS, then across the 64 rows via shuffle. M/q/const are wave-uniform ->
// s_load (SMEM) + v_fmac with SGPR operand; x stays in VGPRs.
// ============================================================================
__global__ __launch_bounds__(512) void main_kernel(
    const float* __restrict__ X, const float* __restrict__ M,
    const float* __restrict__ q, const float* __restrict__ cst,
    float2* __restrict__ partials)
{
    const int tid = threadIdx.x;
    const int lane = tid & 63;
    const int wave = tid >> 6;  // 0..7
    const int n = blockIdx.x * 64 + lane;
    const int wu = __builtin_amdgcn_readfirstlane(wave);

    float x[DIM];
    const float4* X4 = (const float4*)X + n * (DIM / 4);
#pragma unroll
    for (int j4 = 0; j4 < DIM / 4; ++j4) {
        float4 v = X4[j4];
        x[4 * j4 + 0] = v.x; x[4 * j4 + 1] = v.y;
        x[4 * j4 + 2] = v.z; x[4 * j4 + 3] = v.w;
    }

    float m_r = -3.0e38f, s_r = 0.f;
#pragma unroll 1
    for (int kk = 0; kk < 4; ++kk) {
        const int k = wu + kk * 8;  // uniform
        const float* __restrict__ Mk = M + k * DIM * DIM;
        const float* __restrict__ qk = q + k * DIM;
        float maha = 0.f;
#pragma unroll
        for (int ib = 0; ib < 4; ++ib) {
            const int JMAX = (ib + 1) * 16;  // constant after unroll
#pragma unroll
            for (int i2 = 0; i2 < 16; ++i2) {
                const int i = ib * 16 + i2;
                float y = -qk[i];
#pragma unroll
                for (int j = 0; j < JMAX; ++j)
                    y = fmaf(Mk[i * DIM + j], x[j], y);  // M dense-stored, zeros above diag
                maha = fmaf(y, y, maha);
            }
        }
        float logp = fmaf(-0.5f, maha, cst[k]);
        float mn = fmaxf(m_r, logp);
        s_r = s_r * __expf(m_r - mn) + __expf(logp - mn);
        m_r = mn;
    }

    __shared__ float redm[8][64];
    __shared__ float reds[8][64];
    redm[wave][lane] = m_r;
    reds[wave][lane] = s_r;
    __syncthreads();

    if (wave == 0) {
        float mm = redm[0][lane], ss = reds[0][lane];
#pragma unroll
        for (int w2 = 1; w2 < 8; ++w2) {
            float m2 = redm[w2][lane], s2 = reds[w2][lane];
            float mn = fmaxf(mm, m2);
            ss = ss * __expf(mm - mn) + s2 * __expf(m2 - mn);
            mm = mn;
        }
        // loglik for row n; now logsumexp across the 64 rows of this block
        float bm = mm + logf(ss), bs = 1.f;
#pragma unroll
        for (int off = 32; off > 0; off >>= 1) {
            float om = __shfl_xor(bm, off, 64);
            float os = __shfl_xor(bs, off, 64);
            float mn = fmaxf(bm, om);
            bs = bs * __expf(bm - mn) + os * __expf(om - mn);
            bm = mn;
        }
        if (lane == 0) partials[blockIdx.x] = make_float2(bm, bs);
    }
}

// ============================================================================
// Final: merge 512 block partials -> scalar
// ============================================================================
__global__ __launch_bounds__(64) void final_kernel(
    const float2* __restrict__ partials, int nparts, float* __restrict__ out)
{
    const int lane = threadIdx.x;
    float mm = -3.0e38f, ss = 0.f;
    for (int i = lane; i < nparts; i += 64) {
        float2 p = partials[i];
        float mn = fmaxf(mm, p.x);
        ss = ss * __expf(mm - mn) + p.y * __expf(p.x - mn);
        mm = mn;
    }
#pragma unroll
    for (int off = 32; off > 0; off >>= 1) {
        float om = __shfl_xor(mm, off, 64);
        float os = __shfl_xor(ss, off, 64);
        float mn = fmaxf(mm, om);
        ss = ss * __expf(mm - mn) + os * __expf(om - mn);
        mm = mn;
    }
    if (lane == 0) out[0] = -(mm + logf(ss));
}

extern "C" void kernel_launch(void* const* d_in, const int* in_sizes, int n_in,
                              void* d_out, int out_size, void* d_ws, size_t ws_size,
                              hipStream_t stream) {
    const float* X  = (const float*)d_in[0];   // [32768,64]
    const float* mu = (const float*)d_in[1];   // [32,64]
    const float* L  = (const float*)d_in[2];   // [32,64,64]
    const float* w  = (const float*)d_in[3];   // [32]
    // d_in[4] = it (unused)

    float* ws   = (float*)d_ws;
    float* Mbuf = ws;                       // 32*4096 floats
    float* qbuf = Mbuf + KC * DIM * DIM;    // 32*64
    float* cbuf = qbuf + KC * DIM;          // 32
    float2* parts = (float2*)(cbuf + KC);   // 512 float2 (8-byte aligned)

    prep_kernel<<<KC, 64, 0, stream>>>(L, mu, w, Mbuf, qbuf, cbuf);
    main_kernel<<<NPTS / 64, 512, 0, stream>>>(X, Mbuf, qbuf, cbuf, parts);
    final_kernel<<<1, 64, 0, stream>>>(parts, NPTS / 64, (float*)d_out);
}